// Round 2
// baseline (754.828 us; speedup 1.0000x reference)
//
#include <hip/hip_runtime.h>
#include <cstdint>
#include <cstddef>

#define ND 256          // embedding dim
#define NK 4096         // num codes
#define NROWS 65536     // 32*2048
#define M_OUT 16777216  // NROWS*ND
#define IDX_OFF (M_OUT + 4)

// ---------------- workspace layout (bytes) ----------------
#define WS_INV64   0                        // double[65536]  512KB
#define WS_E2_64   (512*1024)               // double[4096]   32KB
#define WS_EH      (WS_E2_64 + 32*1024)     // f16[1M]        2MB
#define WS_BESTIDX (WS_EH + 2*1024*1024)    // int[65536]     256KB
#define WS_COUNTS  (WS_BESTIDX + 256*1024)  // int[4096]      16KB
#define WS_RCOUNT  (WS_COUNTS + 16*1024)    // int[1] + pad   16B
#define WS_RROWS   (WS_RCOUNT + 16)         // int[65536]     256KB
#define WS_PART    (WS_RROWS + 256*1024)    // double[16384]  128KB

typedef _Float16 f16x8 __attribute__((ext_vector_type(8)));
typedef _Float16 f16x4v __attribute__((ext_vector_type(4)));
typedef __attribute__((ext_vector_type(4))) float f32x4;

// async 16B global->LDS (direct-to-shared DMA); lds dest must be wave-uniform base
__device__ __forceinline__ void gll16(const void* g, void* l) {
  __builtin_amdgcn_global_load_lds(
      (const __attribute__((address_space(1))) unsigned int*)g,
      (__attribute__((address_space(3))) unsigned int*)l, 16, 0, 0);
}

// ---------------- kernel 1: row norms + normalized fp16 plane ----------------
__global__ void rownorm_k(const float* __restrict__ z, double* __restrict__ inv64,
                          unsigned short* __restrict__ zh) {
  const int w = threadIdx.x >> 6, lane = threadIdx.x & 63;
  const int row = blockIdx.x * 4 + w;
  const float4 v = *reinterpret_cast<const float4*>(z + (size_t)row * ND + lane * 4);
  double s = (double)v.x * v.x + (double)v.y * v.y + (double)v.z * v.z + (double)v.w * v.w;
  #pragma unroll
  for (int m = 32; m; m >>= 1) s += __shfl_xor(s, m, 64);
  double nrm = sqrt(s);
  if (nrm < 1e-12) nrm = 1e-12;
  const double inv = 1.0 / nrm;
  if (lane == 0) inv64[row] = inv;
  f16x4v h;
  h[0] = (_Float16)(float)(v.x * inv);
  h[1] = (_Float16)(float)(v.y * inv);
  h[2] = (_Float16)(float)(v.z * inv);
  h[3] = (_Float16)(float)(v.w * inv);
  *reinterpret_cast<f16x4v*>(reinterpret_cast<_Float16*>(zh) + (size_t)row * ND + lane * 4) = h;
}

// ---------------- kernel 2: code norms (fp64, for exact recheck) + fp16 plane ----------------
__global__ void embnorm_k(const float* __restrict__ e, double* __restrict__ e2_64,
                          unsigned short* __restrict__ eh) {
  const int w = threadIdx.x >> 6, lane = threadIdx.x & 63;
  const int row = blockIdx.x * 4 + w;
  const float4 v = *reinterpret_cast<const float4*>(e + (size_t)row * ND + lane * 4);
  double s = (double)v.x * v.x + (double)v.y * v.y + (double)v.z * v.z + (double)v.w * v.w;
  #pragma unroll
  for (int m = 32; m; m >>= 1) s += __shfl_xor(s, m, 64);
  if (lane == 0) e2_64[row] = s;
  f16x4v h;
  h[0] = (_Float16)v.x; h[1] = (_Float16)v.y; h[2] = (_Float16)v.z; h[3] = (_Float16)v.w;
  *reinterpret_cast<f16x4v*>(reinterpret_cast<_Float16*>(eh) + (size_t)row * ND + lane * 4) = h;
}

// ---------------- kernel 3: fp16 MFMA GEMM screening + argmin (+2nd best) ----------------
// 128 rows x 128 codes per block; 4 waves (2x2); single product (codes unit-norm ->
// argmin(dist) == argmin(-dot)). Double-buffered LDS with COUNTED vmcnt pipeline (T4):
// per step: [STAGE(s+1); s_waitcnt vmcnt(8); s_barrier; ds_read+MFMA; lgkmcnt(0); s_barrier]
// -> the prefetch issued this step stays in flight across both barriers; the wait only
// covers loads issued a full iteration (~>600cy) earlier. Never vmcnt(0) in main loop.
#define MB 128
#define NB 128
#define BK 64
#define NSTEP 128      // 32 column-tiles x 4 K-steps
#define MARGIN 4e-4f   // in -dot units (== 8e-4 in score units); fp16 dot err <~2e-4 bound

__launch_bounds__(256, 2)
__global__ void phase1_k(const unsigned short* __restrict__ zh_, const unsigned short* __restrict__ eh_,
                         int* __restrict__ best_idx, int* __restrict__ rcount,
                         int* __restrict__ rrows) {
  __shared__ __align__(16) _Float16 smem[2 * 16384];  // 65536 B: 2 buffers x (A 8192 + B 8192 halves)
  const _Float16* zh = reinterpret_cast<const _Float16*>(zh_);
  const _Float16* eh = reinterpret_cast<const _Float16*>(eh_);

  const int t = threadIdx.x;
  const int l = t & 63;
  const int wave = t >> 6;
  const int wm = wave & 1;   // row half
  const int wn = wave >> 1;  // code half
  const int l15 = l & 15, l4 = l >> 4;
  const int row0 = blockIdx.x * MB;

  // staging geometry: within a 16KB plane, byte o = wave*4096 + j*1024 + l*16
  // -> row = o>>7, stored seg = (o>>4)&7, source seg = stored ^ (row&7)
  int rowo[4], sego[4];
  const _Float16* aof[4];
  const _Float16* bof[4];
  #pragma unroll
  for (int j = 0; j < 4; ++j) {
    const int o = wave * 4096 + j * 1024 + l * 16;
    rowo[j] = o >> 7;
    sego[j] = ((o >> 4) & 7) ^ (rowo[j] & 7);
    aof[j] = zh + (size_t)(row0 + rowo[j]) * ND + sego[j] * 8;
    bof[j] = eh + (size_t)rowo[j] * ND + sego[j] * 8;
  }

  // stage step s (s = ct*4+ks) into buffer s&1; 8 global_load_lds per thread
  auto STAGE = [&](int s) {
    const int b = s & 1;
    const int d0 = (s & 3) * BK;
    const size_t cofs = (size_t)(s >> 2) * (NB * ND);
    _Float16* dst = smem + b * 16384 + wave * 2048;
    #pragma unroll
    for (int j = 0; j < 4; ++j) {
      gll16(aof[j] + d0,        dst + j * 512);          // A
      gll16(bof[j] + cofs + d0, dst + j * 512 + 8192);   // B
    }
  };

  float b1[16], b2[16];
  int i1[16];
  #pragma unroll
  for (int s = 0; s < 16; ++s) { b1[s] = 3.4e38f; b2[s] = 3.4e38f; i1[s] = 0; }

  f32x4 acc[4][4];

  STAGE(0);

  for (int s = 0; s < NSTEP; ++s) {
    const int ks = s & 3;
    if (ks == 0) {
      #pragma unroll
      for (int mt = 0; mt < 4; ++mt)
        #pragma unroll
        for (int nt = 0; nt < 4; ++nt) acc[mt][nt] = (f32x4){0.f, 0.f, 0.f, 0.f};
    }

    // prefetch next step into the other buffer; released by last iteration's R-barrier
    if (s + 1 < NSTEP) {
      STAGE(s + 1);
      asm volatile("s_waitcnt vmcnt(8)" ::: "memory");  // wait L(s) only; L(s+1) stays in flight
    } else {
      asm volatile("s_waitcnt vmcnt(0)" ::: "memory");  // last step: drain L(s)
    }
    __builtin_amdgcn_sched_barrier(0);
    __builtin_amdgcn_s_barrier();      // A: all waves' L(s) landed -> buffer s&1 ready
    __builtin_amdgcn_sched_barrier(0);

    const _Float16* Ab = smem + (s & 1) * 16384;
    const _Float16* Bb = Ab + 8192;
    #pragma unroll
    for (int kk = 0; kk < 2; ++kk) {
      f16x8 aF[4], bF[4];
      #pragma unroll
      for (int mt = 0; mt < 4; ++mt) {
        const int ar = wm * 64 + mt * 16 + l15;
        const int sg = (kk * 4 + l4) ^ (ar & 7);
        aF[mt] = *reinterpret_cast<const f16x8*>(&Ab[ar * BK + sg * 8]);
      }
      #pragma unroll
      for (int nt = 0; nt < 4; ++nt) {
        const int br = wn * 64 + nt * 16 + l15;
        const int sg = (kk * 4 + l4) ^ (br & 7);
        bF[nt] = *reinterpret_cast<const f16x8*>(&Bb[br * BK + sg * 8]);
      }
      #pragma unroll
      for (int mt = 0; mt < 4; ++mt)
        #pragma unroll
        for (int nt = 0; nt < 4; ++nt)
          acc[mt][nt] = __builtin_amdgcn_mfma_f32_16x16x32_f16(aF[mt], bF[nt], acc[mt][nt], 0, 0, 0);
    }

    // per-column-tile argmin fold: register-only, sits between A-barrier and R-barrier
    if (ks == 3) {
      const int cbase = (s >> 2) * NB;
      #pragma unroll
      for (int nt = 0; nt < 4; ++nt) {
        const int c = cbase + wn * 64 + nt * 16 + l15;
        #pragma unroll
        for (int mt = 0; mt < 4; ++mt) {
          #pragma unroll
          for (int r = 0; r < 4; ++r) {
            const float sc = -acc[mt][nt][r];   // score == -dot (e2 == 1 for all codes)
            const int slot = mt * 4 + r;
            if (sc < b1[slot]) { b2[slot] = b1[slot]; b1[slot] = sc; i1[slot] = c; }
            else if (sc < b2[slot]) { b2[slot] = sc; }
          }
        }
      }
    }

    // R: all waves consumed buffer s&1 (lgkmcnt(0) drains this wave's ds_reads) ->
    // next iteration's STAGE may overwrite it
    asm volatile("s_waitcnt lgkmcnt(0)" ::: "memory");
    __builtin_amdgcn_sched_barrier(0);
    __builtin_amdgcn_s_barrier();
    __builtin_amdgcn_sched_barrier(0);
  }

  // butterfly merge across the 16 lanes (l&15) sharing each row
  #pragma unroll
  for (int s = 0; s < 16; ++s) {
    #pragma unroll
    for (int m = 1; m < 16; m <<= 1) {
      const float ob1 = __shfl_xor(b1[s], m, 64);
      const float ob2 = __shfl_xor(b2[s], m, 64);
      const int oi1 = __shfl_xor(i1[s], m, 64);
      if (ob1 < b1[s] || (ob1 == b1[s] && oi1 < i1[s])) {
        b2[s] = fminf(b1[s], ob2);
        b1[s] = ob1; i1[s] = oi1;
      } else {
        b2[s] = fminf(b2[s], ob1);
      }
    }
  }

  // cross-wave (wn=0/1) merge via small LDS
  __syncthreads();
  float* M1 = reinterpret_cast<float*>(smem);  // [128][2]
  float* M2 = M1 + 256;                        // [128][2]
  int*   MI = (int*)(M1 + 512);                // [128][2]
  if (l15 == 0) {
    #pragma unroll
    for (int s = 0; s < 16; ++s) {
      const int mt = s >> 2, r = s & 3;
      const int rl = wm * 64 + mt * 16 + l4 * 4 + r;
      M1[rl * 2 + wn] = b1[s];
      M2[rl * 2 + wn] = b2[s];
      MI[rl * 2 + wn] = i1[s];
    }
  }
  __syncthreads();
  if (t < MB) {
    float B1 = M1[t * 2], B2 = M2[t * 2];
    int I1 = MI[t * 2];
    const float y1 = M1[t * 2 + 1], y2 = M2[t * 2 + 1];
    const int yi = MI[t * 2 + 1];
    if (y1 < B1 || (y1 == B1 && yi < I1)) {
      B2 = fminf(B1, y2);
      B1 = y1; I1 = yi;
    } else {
      B2 = fminf(B2, y1);
    }
    const int row = row0 + t;
    best_idx[row] = I1;
    if (B2 - B1 < MARGIN) {  // ambiguous at fp16 precision -> exact recheck
      const int pos = atomicAdd(rcount, 1);
      rrows[pos] = row;
    }
  }
}

// ---------------- kernel 4: exact fp64 recheck, 8 flagged rows per block ----------------
#define P2R 8
__global__ void phase2_k(const float* __restrict__ z, const float* __restrict__ emb,
                         const double* __restrict__ e2_64, const double* __restrict__ inv64,
                         const int* __restrict__ rcount, const int* __restrict__ rrows,
                         int* __restrict__ best_idx) {
  __shared__ double zn[P2R][ND];   // 16KB
  __shared__ double RB[256];
  __shared__ int RI[256];
  const int t = threadIdx.x;
  int cnt = rcount[0];
  if (cnt > NROWS) cnt = NROWS;
  const int ngrp = (cnt + P2R - 1) / P2R;
  for (int g = blockIdx.x; g < ngrp; g += gridDim.x) {
    const int base = g * P2R;
    int nr = cnt - base;
    if (nr > P2R) nr = P2R;
    __syncthreads();
    for (int r = 0; r < nr; ++r) {
      const int row = rrows[base + r];
      zn[r][t] = (double)z[(size_t)row * ND + t] * inv64[row];
    }
    for (int r = nr; r < P2R; ++r) zn[r][t] = 0.0;  // keep lanes finite
    __syncthreads();
    double B[P2R]; int I[P2R];
    #pragma unroll
    for (int r = 0; r < P2R; ++r) { B[r] = 1e300; I[r] = 0; }
    for (int c0 = 0; c0 < 16; ++c0) {
      const int c = t * 16 + c0;  // ascending within thread -> lowest-index on tie
      const float* er = emb + (size_t)c * ND;
      double dot[P2R];
      #pragma unroll
      for (int r = 0; r < P2R; ++r) dot[r] = 0.0;
      for (int d = 0; d < ND; d += 4) {
        const float4 ev = *reinterpret_cast<const float4*>(er + d);
        #pragma unroll
        for (int r = 0; r < P2R; ++r)
          dot[r] += zn[r][d] * (double)ev.x + zn[r][d + 1] * (double)ev.y +
                    zn[r][d + 2] * (double)ev.z + zn[r][d + 3] * (double)ev.w;
      }
      #pragma unroll
      for (int r = 0; r < P2R; ++r) {
        const double s = e2_64[c] - 2.0 * dot[r];
        if (s < B[r]) { B[r] = s; I[r] = c; }
      }
    }
    for (int r = 0; r < nr; ++r) {
      RB[t] = B[r]; RI[t] = I[r];
      __syncthreads();
      for (int off = 128; off; off >>= 1) {
        if (t < off) {
          const double sb = RB[t + off];
          const int si = RI[t + off];
          if (sb < RB[t] || (sb == RB[t] && si < RI[t])) { RB[t] = sb; RI[t] = si; }
        }
        __syncthreads();
      }
      if (t == 0) best_idx[rrows[base + r]] = RI[0];
      __syncthreads();
    }
  }
}

// ---------------- kernel 5: gather z_q, loss partials, histogram, index output ----------------
__global__ void gather_k(const float* __restrict__ z, const float* __restrict__ emb,
                         const int* __restrict__ best_idx, const double* __restrict__ inv64,
                         float* __restrict__ out, double* __restrict__ partials,
                         int* __restrict__ counts) {
  __shared__ double wsum[4];
  const int w = threadIdx.x >> 6, lane = threadIdx.x & 63;
  const int row = blockIdx.x * 4 + w;
  const int idx = best_idx[row];
  const double inv = inv64[row];
  const float4 zv = *reinterpret_cast<const float4*>(z + (size_t)row * ND + lane * 4);
  const float4 ev = *reinterpret_cast<const float4*>(emb + (size_t)idx * ND + lane * 4);
  *reinterpret_cast<float4*>(out + (size_t)row * ND + lane * 4) = ev;  // z_q_st == z_q
  const double dx = (double)ev.x - (double)zv.x * inv;
  const double dy = (double)ev.y - (double)zv.y * inv;
  const double dz = (double)ev.z - (double)zv.z * inv;
  const double dw = (double)ev.w - (double)zv.w * inv;
  double s = dx * dx + dy * dy + dz * dz + dw * dw;
  #pragma unroll
  for (int m = 32; m; m >>= 1) s += __shfl_xor(s, m, 64);
  if (lane == 0) {
    wsum[w] = s;
    atomicAdd(&counts[idx], 1);
    out[IDX_OFF + row] = (float)idx;
  }
  __syncthreads();
  if (threadIdx.x == 0) partials[blockIdx.x] = wsum[0] + wsum[1] + wsum[2] + wsum[3];
}

// ---------------- kernel 6: scalars (losses + perplexity) ----------------
__global__ void finalize_k(const double* __restrict__ partials, const int* __restrict__ counts,
                           float* __restrict__ out) {
  __shared__ double red[256];
  const int t = threadIdx.x;
  double s = 0.0;
  for (int k = 0; k < 64; ++k) s += partials[t + 256 * k];
  red[t] = s;
  __syncthreads();
  for (int off = 128; off; off >>= 1) {
    if (t < off) red[t] += red[t + off];
    __syncthreads();
  }
  const double c = red[0] / (double)M_OUT;  // codebook_loss == commitment_loss
  __syncthreads();
  double h = 0.0;
  for (int k = 0; k < 16; ++k) {
    const double p = (double)counts[t * 16 + k] * (1.0 / 65536.0);
    h += p * log(p + 1e-10);
  }
  red[t] = h;
  __syncthreads();
  for (int off = 128; off; off >>= 1) {
    if (t < off) red[t] += red[t + off];
    __syncthreads();
  }
  if (t == 0) {
    const double perp = exp(-red[0]);
    out[M_OUT + 0] = (float)(c + 0.25 * c);  // vq_loss = codebook + BETA*commitment
    out[M_OUT + 1] = (float)c;               // codebook_loss
    out[M_OUT + 2] = (float)c;               // commitment_loss
    out[M_OUT + 3] = (float)perp;            // perplexity
  }
}

extern "C" void kernel_launch(void* const* d_in, const int* in_sizes, int n_in,
                              void* d_out, int out_size, void* d_ws, size_t ws_size,
                              hipStream_t stream) {
  const float* z = (const float*)d_in[0];
  const float* emb = (const float*)d_in[1];
  float* out = (float*)d_out;
  char* ws = (char*)d_ws;
  double* inv64   = (double*)(ws + WS_INV64);
  double* e2_64   = (double*)(ws + WS_E2_64);
  unsigned short* eh = (unsigned short*)(ws + WS_EH);
  int*    best_i  = (int*)(ws + WS_BESTIDX);
  int*    counts  = (int*)(ws + WS_COUNTS);
  int*    rcount  = (int*)(ws + WS_RCOUNT);
  int*    rrows   = (int*)(ws + WS_RROWS);
  double* partials = (double*)(ws + WS_PART);
  // z fp16 plane lives in d_out[0..8M floats) -- fully overwritten by gather_k later
  unsigned short* zh = (unsigned short*)d_out;  // [65536][256] f16

  hipMemsetAsync(ws + WS_COUNTS, 0, 16 * 1024 + 16, stream);  // counts + rcount
  rownorm_k<<<NROWS / 4, 256, 0, stream>>>(z, inv64, zh);
  embnorm_k<<<NK / 4, 256, 0, stream>>>(emb, e2_64, eh);
  phase1_k<<<NROWS / MB, 256, 0, stream>>>(zh, eh, best_i, rcount, rrows);
  phase2_k<<<1024, 256, 0, stream>>>(z, emb, e2_64, inv64, rcount, rrows, best_i);
  gather_k<<<NROWS / 4, 256, 0, stream>>>(z, emb, best_i, inv64, out, partials, counts);
  finalize_k<<<1, 256, 0, stream>>>(partials, counts, out);
}

// Round 3
// 619.521 us; speedup vs baseline: 1.2184x; 1.2184x over previous
//
#include <hip/hip_runtime.h>
#include <cstdint>
#include <cstddef>

#define ND 256          // embedding dim
#define NK 4096         // num codes
#define NROWS 65536     // 32*2048
#define M_OUT 16777216  // NROWS*ND
#define IDX_OFF (M_OUT + 4)

// ---------------- workspace layout (bytes) ----------------
#define WS_INV64   0                        // double[65536]  512KB
#define WS_E2_64   (512*1024)               // double[4096]   32KB
#define WS_EH      (WS_E2_64 + 32*1024)     // f16[1M]        2MB
#define WS_BESTIDX (WS_EH + 2*1024*1024)    // int[65536]     256KB
#define WS_COUNTS  (WS_BESTIDX + 256*1024)  // int[4096]      16KB
#define WS_RCOUNT  (WS_COUNTS + 16*1024)    // int[1] + pad   16B
#define WS_RROWS   (WS_RCOUNT + 16)         // int[65536]     256KB
#define WS_PART    (WS_RROWS + 256*1024)    // double[16384]  128KB

typedef _Float16 f16x8 __attribute__((ext_vector_type(8)));
typedef _Float16 f16x4v __attribute__((ext_vector_type(4)));
typedef __attribute__((ext_vector_type(4))) float f32x4;

// async 16B global->LDS (direct-to-shared DMA); lds dest must be wave-uniform base
__device__ __forceinline__ void gll16(const void* g, void* l) {
  __builtin_amdgcn_global_load_lds(
      (const __attribute__((address_space(1))) unsigned int*)g,
      (__attribute__((address_space(3))) unsigned int*)l, 16, 0, 0);
}

// ---------------- kernel 1: row norms + normalized fp16 plane ----------------
__global__ void rownorm_k(const float* __restrict__ z, double* __restrict__ inv64,
                          unsigned short* __restrict__ zh) {
  const int w = threadIdx.x >> 6, lane = threadIdx.x & 63;
  const int row = blockIdx.x * 4 + w;
  const float4 v = *reinterpret_cast<const float4*>(z + (size_t)row * ND + lane * 4);
  double s = (double)v.x * v.x + (double)v.y * v.y + (double)v.z * v.z + (double)v.w * v.w;
  #pragma unroll
  for (int m = 32; m; m >>= 1) s += __shfl_xor(s, m, 64);
  double nrm = sqrt(s);
  if (nrm < 1e-12) nrm = 1e-12;
  const double inv = 1.0 / nrm;
  if (lane == 0) inv64[row] = inv;
  f16x4v h;
  h[0] = (_Float16)(float)(v.x * inv);
  h[1] = (_Float16)(float)(v.y * inv);
  h[2] = (_Float16)(float)(v.z * inv);
  h[3] = (_Float16)(float)(v.w * inv);
  *reinterpret_cast<f16x4v*>(reinterpret_cast<_Float16*>(zh) + (size_t)row * ND + lane * 4) = h;
}

// ---------------- kernel 2: code norms (fp64, for exact recheck) + fp16 plane ----------------
__global__ void embnorm_k(const float* __restrict__ e, double* __restrict__ e2_64,
                          unsigned short* __restrict__ eh) {
  const int w = threadIdx.x >> 6, lane = threadIdx.x & 63;
  const int row = blockIdx.x * 4 + w;
  const float4 v = *reinterpret_cast<const float4*>(e + (size_t)row * ND + lane * 4);
  double s = (double)v.x * v.x + (double)v.y * v.y + (double)v.z * v.z + (double)v.w * v.w;
  #pragma unroll
  for (int m = 32; m; m >>= 1) s += __shfl_xor(s, m, 64);
  if (lane == 0) e2_64[row] = s;
  f16x4v h;
  h[0] = (_Float16)v.x; h[1] = (_Float16)v.y; h[2] = (_Float16)v.z; h[3] = (_Float16)v.w;
  *reinterpret_cast<f16x4v*>(reinterpret_cast<_Float16*>(eh) + (size_t)row * ND + lane * 4) = h;
}

// ---------------- kernel 3: fp16 MFMA GEMM screening + argmin (+2nd best) ----------------
// m97-structure: 64 rows x 128 codes per block; 4 waves (2x2); SINGLE-buffered 24KB LDS
// (A 8KB + B 16KB), two __syncthreads per K-step; 1024 blocks -> 4 blocks/CU (4 waves/SIMD)
// so cross-block TLP hides the stage+drain latency (m114 implicit overlap).
// Codes are unit-norm -> argmin(dist) == argmax(dot); track top-2 via median identity.
#define MB 64
#define NB 128
#define BK 64
#define MARGIN 4e-4f   // in dot units (== 8e-4 in score units); fp16 dot err <~2e-4 bound

__launch_bounds__(256, 4)
__global__ void phase1_k(const unsigned short* __restrict__ zh_, const unsigned short* __restrict__ eh_,
                         int* __restrict__ best_idx, int* __restrict__ rcount,
                         int* __restrict__ rrows) {
  __shared__ __align__(16) _Float16 smem[4096 + 8192];  // A [64][64] + B [128][64] = 24576 B
  const _Float16* zh = reinterpret_cast<const _Float16*>(zh_);
  const _Float16* eh = reinterpret_cast<const _Float16*>(eh_);

  const int t = threadIdx.x;
  const int l = t & 63;
  const int wave = t >> 6;
  const int wm = wave & 1;   // row half
  const int wn = wave >> 1;  // code half
  const int l15 = l & 15, l4 = l >> 4;
  const int row0 = blockIdx.x * MB;

  // staging geometry: within a plane, byte o = wave*1024 + j*4096 + l*16
  // -> row = o>>7 (128B/row), stored seg = (o>>4)&7, source seg = stored ^ (row&7)
  const _Float16* aptr[2];     // A: 2 chunks/thread (8KB plane)
  int bofs[4];                 // B: 4 chunks/thread (16KB plane), element offsets
  #pragma unroll
  for (int j = 0; j < 2; ++j) {
    const int o = wave * 1024 + j * 4096 + l * 16;
    const int r = o >> 7;
    const int sg = ((o >> 4) & 7) ^ (r & 7);
    aptr[j] = zh + (size_t)(row0 + r) * ND + sg * 8;
  }
  #pragma unroll
  for (int j = 0; j < 4; ++j) {
    const int o = wave * 1024 + j * 4096 + l * 16;
    const int r = o >> 7;
    const int sg = ((o >> 4) & 7) ^ (r & 7);
    bofs[j] = r * ND + sg * 8;
  }

  // top-2 max-dot tracking per slot (slot = mt*4 + r), index tie-break = first (lowest c)
  float m1[8], m2[8];
  int i1[8];
  #pragma unroll
  for (int s = 0; s < 8; ++s) { m1[s] = -3.4e38f; m2[s] = -3.4e38f; i1[s] = 0; }
  int cvec[4];
  #pragma unroll
  for (int nt = 0; nt < 4; ++nt) cvec[nt] = wn * 64 + nt * 16 + l15;

  f32x4 acc[2][4];

  for (int s = 0; s < 128; ++s) {          // 32 column-tiles x 4 K-steps
    const int ks = s & 3;
    if (ks == 0) {
      #pragma unroll
      for (int mt = 0; mt < 2; ++mt)
        #pragma unroll
        for (int nt = 0; nt < 4; ++nt) acc[mt][nt] = (f32x4){0.f, 0.f, 0.f, 0.f};
    }

    __syncthreads();   // all waves done reading buffer (previous step)
    {
      const int d0 = ks * BK;
      const size_t cofs = (size_t)(s >> 2) * (NB * ND);
      #pragma unroll
      for (int j = 0; j < 2; ++j)
        gll16(aptr[j] + d0, smem + wave * 512 + j * 2048);
      #pragma unroll
      for (int j = 0; j < 4; ++j)
        gll16(eh + cofs + bofs[j] + d0, smem + 4096 + wave * 512 + j * 2048);
    }
    __syncthreads();   // drains vmcnt -> buffer ready (stall hidden by other blocks on CU)

    #pragma unroll
    for (int kk = 0; kk < 2; ++kk) {
      f16x8 aF[2], bF[4];
      #pragma unroll
      for (int mt = 0; mt < 2; ++mt) {
        const int ar = wm * 32 + mt * 16 + l15;
        const int sg = (kk * 4 + l4) ^ (ar & 7);
        aF[mt] = *reinterpret_cast<const f16x8*>(&smem[ar * BK + sg * 8]);
      }
      #pragma unroll
      for (int nt = 0; nt < 4; ++nt) {
        const int br = wn * 64 + nt * 16 + l15;
        const int sg = (kk * 4 + l4) ^ (br & 7);
        bF[nt] = *reinterpret_cast<const f16x8*>(&smem[4096 + br * BK + sg * 8]);
      }
      #pragma unroll
      for (int mt = 0; mt < 2; ++mt)
        #pragma unroll
        for (int nt = 0; nt < 4; ++nt)
          acc[mt][nt] = __builtin_amdgcn_mfma_f32_16x16x32_f16(aF[mt], bF[nt], acc[mt][nt], 0, 0, 0);
    }

    // per-column-tile top-2 fold (register-only, ~5 VALU/value via median identity)
    if (ks == 3) {
      const int cbase = (s >> 2) * NB;
      #pragma unroll
      for (int nt = 0; nt < 4; ++nt) {
        const int c = cbase + cvec[nt];
        #pragma unroll
        for (int mt = 0; mt < 2; ++mt) {
          #pragma unroll
          for (int r = 0; r < 4; ++r) {
            const float d = acc[mt][nt][r];
            const int slot = mt * 4 + r;
            m2[slot] = fmaxf(m2[slot], fminf(d, m1[slot]));  // median(d, m1, m2)
            if (d > m1[slot]) i1[slot] = c;                  // strict > keeps lowest c on tie
            m1[slot] = fmaxf(m1[slot], d);
          }
        }
      }
    }
  }

  // convert to min-score form for the merges: score = -dot
  float b1[8], b2[8];
  #pragma unroll
  for (int s = 0; s < 8; ++s) { b1[s] = -m1[s]; b2[s] = -m2[s]; }

  // butterfly merge across the 16 lanes (l&15) sharing each row
  #pragma unroll
  for (int s = 0; s < 8; ++s) {
    #pragma unroll
    for (int m = 1; m < 16; m <<= 1) {
      const float ob1 = __shfl_xor(b1[s], m, 64);
      const float ob2 = __shfl_xor(b2[s], m, 64);
      const int oi1 = __shfl_xor(i1[s], m, 64);
      if (ob1 < b1[s] || (ob1 == b1[s] && oi1 < i1[s])) {
        b2[s] = fminf(b1[s], ob2);
        b1[s] = ob1; i1[s] = oi1;
      } else {
        b2[s] = fminf(b2[s], ob1);
      }
    }
  }

  // cross-wave (wn=0/1) merge via small LDS
  __syncthreads();
  float* M1 = reinterpret_cast<float*>(smem);  // [64][2]
  float* M2 = M1 + 128;                        // [64][2]
  int*   MI = (int*)(M1 + 256);                // [64][2]
  if (l15 == 0) {
    #pragma unroll
    for (int s = 0; s < 8; ++s) {
      const int mt = s >> 2, r = s & 3;
      const int rl = wm * 32 + mt * 16 + l4 * 4 + r;
      M1[rl * 2 + wn] = b1[s];
      M2[rl * 2 + wn] = b2[s];
      MI[rl * 2 + wn] = i1[s];
    }
  }
  __syncthreads();
  if (t < MB) {
    float B1 = M1[t * 2], B2 = M2[t * 2];
    int I1 = MI[t * 2];
    const float y1 = M1[t * 2 + 1], y2 = M2[t * 2 + 1];
    const int yi = MI[t * 2 + 1];
    if (y1 < B1 || (y1 == B1 && yi < I1)) {
      B2 = fminf(B1, y2);
      B1 = y1; I1 = yi;
    } else {
      B2 = fminf(B2, y1);
    }
    const int row = row0 + t;
    best_idx[row] = I1;
    if (B2 - B1 < MARGIN) {  // ambiguous at fp16 precision -> exact recheck
      const int pos = atomicAdd(rcount, 1);
      rrows[pos] = row;
    }
  }
}

// ---------------- kernel 4: exact fp64 recheck, 8 flagged rows per block ----------------
#define P2R 8
__global__ void phase2_k(const float* __restrict__ z, const float* __restrict__ emb,
                         const double* __restrict__ e2_64, const double* __restrict__ inv64,
                         const int* __restrict__ rcount, const int* __restrict__ rrows,
                         int* __restrict__ best_idx) {
  __shared__ double zn[P2R][ND];   // 16KB
  __shared__ double RB[256];
  __shared__ int RI[256];
  const int t = threadIdx.x;
  int cnt = rcount[0];
  if (cnt > NROWS) cnt = NROWS;
  const int ngrp = (cnt + P2R - 1) / P2R;
  for (int g = blockIdx.x; g < ngrp; g += gridDim.x) {
    const int base = g * P2R;
    int nr = cnt - base;
    if (nr > P2R) nr = P2R;
    __syncthreads();
    for (int r = 0; r < nr; ++r) {
      const int row = rrows[base + r];
      zn[r][t] = (double)z[(size_t)row * ND + t] * inv64[row];
    }
    for (int r = nr; r < P2R; ++r) zn[r][t] = 0.0;  // keep lanes finite
    __syncthreads();
    double B[P2R]; int I[P2R];
    #pragma unroll
    for (int r = 0; r < P2R; ++r) { B[r] = 1e300; I[r] = 0; }
    for (int c0 = 0; c0 < 16; ++c0) {
      const int c = t * 16 + c0;  // ascending within thread -> lowest-index on tie
      const float* er = emb + (size_t)c * ND;
      double dot[P2R];
      #pragma unroll
      for (int r = 0; r < P2R; ++r) dot[r] = 0.0;
      for (int d = 0; d < ND; d += 4) {
        const float4 ev = *reinterpret_cast<const float4*>(er + d);
        #pragma unroll
        for (int r = 0; r < P2R; ++r)
          dot[r] += zn[r][d] * (double)ev.x + zn[r][d + 1] * (double)ev.y +
                    zn[r][d + 2] * (double)ev.z + zn[r][d + 3] * (double)ev.w;
      }
      #pragma unroll
      for (int r = 0; r < P2R; ++r) {
        const double s = e2_64[c] - 2.0 * dot[r];
        if (s < B[r]) { B[r] = s; I[r] = c; }
      }
    }
    for (int r = 0; r < nr; ++r) {
      RB[t] = B[r]; RI[t] = I[r];
      __syncthreads();
      for (int off = 128; off; off >>= 1) {
        if (t < off) {
          const double sb = RB[t + off];
          const int si = RI[t + off];
          if (sb < RB[t] || (sb == RB[t] && si < RI[t])) { RB[t] = sb; RI[t] = si; }
        }
        __syncthreads();
      }
      if (t == 0) best_idx[rrows[base + r]] = RI[0];
      __syncthreads();
    }
  }
}

// ---------------- kernel 5: gather z_q, loss partials, histogram, index output ----------------
__global__ void gather_k(const float* __restrict__ z, const float* __restrict__ emb,
                         const int* __restrict__ best_idx, const double* __restrict__ inv64,
                         float* __restrict__ out, double* __restrict__ partials,
                         int* __restrict__ counts) {
  __shared__ double wsum[4];
  const int w = threadIdx.x >> 6, lane = threadIdx.x & 63;
  const int row = blockIdx.x * 4 + w;
  const int idx = best_idx[row];
  const double inv = inv64[row];
  const float4 zv = *reinterpret_cast<const float4*>(z + (size_t)row * ND + lane * 4);
  const float4 ev = *reinterpret_cast<const float4*>(emb + (size_t)idx * ND + lane * 4);
  *reinterpret_cast<float4*>(out + (size_t)row * ND + lane * 4) = ev;  // z_q_st == z_q
  const double dx = (double)ev.x - (double)zv.x * inv;
  const double dy = (double)ev.y - (double)zv.y * inv;
  const double dz = (double)ev.z - (double)zv.z * inv;
  const double dw = (double)ev.w - (double)zv.w * inv;
  double s = dx * dx + dy * dy + dz * dz + dw * dw;
  #pragma unroll
  for (int m = 32; m; m >>= 1) s += __shfl_xor(s, m, 64);
  if (lane == 0) {
    wsum[w] = s;
    atomicAdd(&counts[idx], 1);
    out[IDX_OFF + row] = (float)idx;
  }
  __syncthreads();
  if (threadIdx.x == 0) partials[blockIdx.x] = wsum[0] + wsum[1] + wsum[2] + wsum[3];
}

// ---------------- kernel 6: scalars (losses + perplexity) ----------------
__global__ void finalize_k(const double* __restrict__ partials, const int* __restrict__ counts,
                           float* __restrict__ out) {
  __shared__ double red[256];
  const int t = threadIdx.x;
  double s = 0.0;
  for (int k = 0; k < 64; ++k) s += partials[t + 256 * k];
  red[t] = s;
  __syncthreads();
  for (int off = 128; off; off >>= 1) {
    if (t < off) red[t] += red[t + off];
    __syncthreads();
  }
  const double c = red[0] / (double)M_OUT;  // codebook_loss == commitment_loss
  __syncthreads();
  double h = 0.0;
  for (int k = 0; k < 16; ++k) {
    const double p = (double)counts[t * 16 + k] * (1.0 / 65536.0);
    h += p * log(p + 1e-10);
  }
  red[t] = h;
  __syncthreads();
  for (int off = 128; off; off >>= 1) {
    if (t < off) red[t] += red[t + off];
    __syncthreads();
  }
  if (t == 0) {
    const double perp = exp(-red[0]);
    out[M_OUT + 0] = (float)(c + 0.25 * c);  // vq_loss = codebook + BETA*commitment
    out[M_OUT + 1] = (float)c;               // codebook_loss
    out[M_OUT + 2] = (float)c;               // commitment_loss
    out[M_OUT + 3] = (float)perp;            // perplexity
  }
}

extern "C" void kernel_launch(void* const* d_in, const int* in_sizes, int n_in,
                              void* d_out, int out_size, void* d_ws, size_t ws_size,
                              hipStream_t stream) {
  const float* z = (const float*)d_in[0];
  const float* emb = (const float*)d_in[1];
  float* out = (float*)d_out;
  char* ws = (char*)d_ws;
  double* inv64   = (double*)(ws + WS_INV64);
  double* e2_64   = (double*)(ws + WS_E2_64);
  unsigned short* eh = (unsigned short*)(ws + WS_EH);
  int*    best_i  = (int*)(ws + WS_BESTIDX);
  int*    counts  = (int*)(ws + WS_COUNTS);
  int*    rcount  = (int*)(ws + WS_RCOUNT);
  int*    rrows   = (int*)(ws + WS_RROWS);
  double* partials = (double*)(ws + WS_PART);
  // z fp16 plane lives in d_out[0..8M floats) -- fully overwritten by gather_k later
  unsigned short* zh = (unsigned short*)d_out;  // [65536][256] f16

  hipMemsetAsync(ws + WS_COUNTS, 0, 16 * 1024 + 16, stream);  // counts + rcount
  rownorm_k<<<NROWS / 4, 256, 0, stream>>>(z, inv64, zh);
  embnorm_k<<<NK / 4, 256, 0, stream>>>(emb, e2_64, eh);
  phase1_k<<<NROWS / MB, 256, 0, stream>>>(zh, eh, best_i, rcount, rrows);
  phase2_k<<<1024, 256, 0, stream>>>(z, emb, e2_64, inv64, rcount, rrows, best_i);
  gather_k<<<NROWS / 4, 256, 0, stream>>>(z, emb, best_i, inv64, out, partials, counts);
  finalize_k<<<1, 256, 0, stream>>>(partials, counts, out);
}